// Round 6
// baseline (735.993 us; speedup 1.0000x reference)
//
#include <hip/hip_runtime.h>
#include <hip/hip_bf16.h>

typedef short s16x8 __attribute__((ext_vector_type(8)));
typedef float f32x4 __attribute__((ext_vector_type(4)));
typedef unsigned short ushort_t;
typedef unsigned int uint;

#define DEV static __device__ __forceinline__

namespace {
constexpr int kV = 27, kS = 10, kB = 32768;
constexpr int BT = 32, NB = kB / BT;   // 1024 blocks, 2 blocks/CU

// fragment-ordered blob offsets (ushort units): [(tile*nF+fi)*512 + lane*8 + e]
constexpr size_t O_BE_R   = 0;
constexpr size_t O_BE_Z   = O_BE_R   + (size_t)7*4*512;
constexpr size_t O_BE_NH  = O_BE_Z   + (size_t)7*4*512;
constexpr size_t O_BE_NHL = O_BE_NH  + (size_t)7*4*512;
constexpr size_t O_BE_NX  = O_BE_NHL + (size_t)7*4*512;
constexpr size_t O_BE_NXL = O_BE_NX  + (size_t)7*1*512;
constexpr size_t O_BD_R   = O_BE_NXL + (size_t)7*1*512;
constexpr size_t O_BD_Z   = O_BD_R   + (size_t)7*8*512;
constexpr size_t O_BD_NC  = O_BD_Z   + (size_t)7*8*512;   // frags {0,1,2,3,7}
constexpr size_t O_BD_NCL = O_BD_NC  + (size_t)7*5*512;
constexpr size_t O_BD_NH  = O_BD_NCL + (size_t)7*5*512;   // frags {4,5,6,7}
constexpr size_t O_BD_NHL = O_BD_NH  + (size_t)7*4*512;
constexpr size_t O_WATT   = O_BD_NHL + (size_t)7*4*512;   // frags {4,5,6,7}
constexpr size_t O_BLIN   = O_WATT   + (size_t)7*4*512;   // frags {4,5,6,7}
constexpr size_t O_BLINL  = O_BLIN   + (size_t)2*4*512;

constexpr int ESTR = 102;              // Esh row stride (ushorts): 51 words, gcd(51,32)=1
constexpr int EPL  = BT * ESTR;        // per-s plane = 3264 ushorts
} // namespace

DEV float sigm(float x) { return 1.f / (1.f + __expf(-x)); }
DEV float tanh_(float x) {
  const float ax = fabsf(x), t = __expf(-2.f * ax);
  return copysignf((1.f - t) / (1.f + t), x);
}
DEV ushort_t f2b(float f) { return __builtin_bit_cast(ushort_t, __float2bfloat16(f)); }
DEV float b2f(ushort_t u) { return __builtin_bit_cast(float, (uint)u << 16); }
DEV float lo16(uint u) { return __builtin_bit_cast(float, u << 16); }
DEV float hi16(uint u) { return __builtin_bit_cast(float, u & 0xFFFF0000u); }
DEV f32x4 MF(s16x8 a, s16x8 b, f32x4 c) {
  return __builtin_amdgcn_mfma_f32_16x16x32_bf16(a, b, c, 0, 0, 0);
}
DEV float dot64(const float* __restrict__ a, const float* __restrict__ b) {
  float s = 0.f;
#pragma unroll 16
  for (int k = 0; k < 64; ++k) s += a[k] * b[k];
  return s;
}
DEV void storeHL(ushort_t* ws, size_t offH, size_t offL, int e, float v) {
  const ushort_t h = f2b(v);
  ws[offH + e] = h;
  ws[offL + e] = f2b(v - b2f(h));
}

// fragment-ordered B load: one coalesced 1KB block per (tile,frag)
DEV s16x8 ldBF(const ushort_t* p, int fragIdx, int lane) {
  return __builtin_bit_cast(s16x8, *(const uint4*)(p + ((size_t)fragIdx << 9) + (lane << 3)));
}
// swizzled A-tile (row stride 512B, XOR (row&7)<<4)
DEV uint swzb(int row, int byteoff) { return (uint)((row * 512 + byteoff) ^ ((row & 7) << 4)); }
DEV s16x8 ldA(const ushort_t* A, int rt, int kf, int cl, int g4) {
  const int row = rt * 16 + cl;
  return __builtin_bit_cast(s16x8, *(const uint4*)((const char*)A + swzb(row, kf * 64 + g4 * 16)));
}
DEV void stA16(ushort_t* A, int row, int col, ushort_t v) {
  *(ushort_t*)((char*)A + swzb(row, col * 2)) = v;
}
DEV void stA32(ushort_t* A, int row, int byteoff, uint v) {
  *(uint*)((char*)A + swzb(row, byteoff)) = v;
}
DEV uint ldA32(const ushort_t* A, int row, int byteoff) {
  return *(const uint*)((const char*)A + swzb(row, byteoff));
}

// ============ setup (unchanged from R5) ============
// Encoder A (K=128): [h 0..99 | oh 100..126 | const1 @127]
// Decoder A (K=256): [ctx 0..99 | pad | h 128..227 | oh 228..254 | const1 @255]
__global__ void seq2seq_setup(const float* __restrict__ emb,
    const float* __restrict__ eWih, const float* __restrict__ eWhh,
    const float* __restrict__ ebih, const float* __restrict__ ebhh,
    const float* __restrict__ dWih, const float* __restrict__ dWhh,
    const float* __restrict__ dbih, const float* __restrict__ dbhh,
    const float* __restrict__ attnW, const float* __restrict__ linW,
    const float* __restrict__ linb, ushort_t* __restrict__ ws) {
  const int t0 = blockIdx.x * blockDim.x + threadIdx.x;
  const int stp = gridDim.x * blockDim.x;

  for (int e = t0; e < 7 * 4 * 512; e += stp) {
    int c = e >> 11, rem = e & 2047, fi = rem >> 9, l = (rem >> 3) & 63, i8 = rem & 7;
    int d = 16 * c + (l & 15);
    int k = fi * 32 + ((l >> 4) << 3) + i8;
    float vr = 0, vz = 0, vnh = 0;
    if (d < 100) {
      if (k < 100) { vr = eWhh[d*100+k]; vz = eWhh[(100+d)*100+k]; vnh = eWhh[(200+d)*100+k]; }
      else if (k < 127) {
        int tok = k - 100;
        vr = dot64(emb + tok*64, eWih + (size_t)d*64);
        vz = dot64(emb + tok*64, eWih + (size_t)(100+d)*64);
      } else {
        vr = ebih[d] + ebhh[d]; vz = ebih[100+d] + ebhh[100+d]; vnh = ebhh[200+d];
      }
    }
    ws[O_BE_R + e] = f2b(vr);
    ws[O_BE_Z + e] = f2b(vz);
    storeHL(ws, O_BE_NH, O_BE_NHL, e, vnh);
  }
  for (int e = t0; e < 7 * 512; e += stp) {
    int c = e >> 9, l = (e >> 3) & 63, i8 = e & 7;
    int d = 16 * c + (l & 15);
    int k = 96 + ((l >> 4) << 3) + i8;
    float v = 0;
    if (d < 100) {
      if (k >= 100 && k < 127) v = dot64(emb + (k-100)*64, eWih + (size_t)(200+d)*64);
      else if (k == 127) v = ebih[200+d];
    }
    storeHL(ws, O_BE_NX, O_BE_NXL, e, v);
  }
  for (int e = t0; e < 7 * 8 * 512; e += stp) {
    int c = e >> 12, rem = e & 4095, fi = rem >> 9, l = (rem >> 3) & 63, i8 = rem & 7;
    int d = 16 * c + (l & 15);
    int k = fi * 32 + ((l >> 4) << 3) + i8;
    float vr = 0, vz = 0;
    if (d < 100) {
      int wr = d, wz = 100 + d;
      if (k < 100)       { vr = dWih[(size_t)wr*164+64+k]; vz = dWih[(size_t)wz*164+64+k]; }
      else if (k < 128)  { }
      else if (k < 228)  { vr = dWhh[wr*100+k-128];        vz = dWhh[wz*100+k-128]; }
      else if (k < 255)  { vr = dot64(emb+(k-228)*64, dWih+(size_t)wr*164);
                           vz = dot64(emb+(k-228)*64, dWih+(size_t)wz*164); }
      else               { vr = dbih[wr]+dbhh[wr];         vz = dbih[wz]+dbhh[wz]; }
    }
    ws[O_BD_R + e] = f2b(vr);
    ws[O_BD_Z + e] = f2b(vz);
  }
  for (int e = t0; e < 7 * 5 * 512; e += stp) {
    int c = e / (5*512), rem = e - c*5*512, fi = rem >> 9, l = (rem >> 3) & 63, i8 = rem & 7;
    int fid = (fi < 4) ? fi : 7;
    int d = 16 * c + (l & 15);
    int k = fid * 32 + ((l >> 4) << 3) + i8;
    float v = 0;
    if (d < 100) {
      int wr = 200 + d;
      if (k < 100) v = dWih[(size_t)wr*164+64+k];
      else if (k >= 228 && k < 255) v = dot64(emb+(k-228)*64, dWih+(size_t)wr*164);
      else if (k == 255) v = dbih[wr];
    }
    storeHL(ws, O_BD_NC, O_BD_NCL, e, v);
  }
  for (int e = t0; e < 7 * 4 * 512; e += stp) {
    int c = e >> 11, rem = e & 2047, fi = rem >> 9, l = (rem >> 3) & 63, i8 = rem & 7;
    int d = 16 * c + (l & 15);
    int k = (4 + fi) * 32 + ((l >> 4) << 3) + i8;
    float v = 0;
    if (d < 100) {
      int wr = 200 + d;
      if (k >= 128 && k < 228) v = dWhh[wr*100+k-128];
      else if (k == 255) v = dbhh[wr];
    }
    storeHL(ws, O_BD_NH, O_BD_NHL, e, v);
  }
  for (int e = t0; e < 7 * 4 * 512; e += stp) {
    int c = e >> 11, rem = e & 2047, fi = rem >> 9, l = (rem >> 3) & 63, i8 = rem & 7;
    int d = 16 * c + (l & 15);
    int k = (4 + fi) * 32 + ((l >> 4) << 3) + i8;
    float v = 0;
    if (d < 100 && k >= 128 && k < 228) v = attnW[(k-128)*100 + d];
    ws[O_WATT + e] = f2b(v);
  }
  for (int e = t0; e < 2 * 4 * 512; e += stp) {
    int c = e >> 11, rem = e & 2047, fi = rem >> 9, l = (rem >> 3) & 63, i8 = rem & 7;
    int vv = 16 * c + (l & 15);
    int k = (4 + fi) * 32 + ((l >> 4) << 3) + i8;
    float v = 0;
    if (vv < kV) {
      if (k >= 128 && k < 228) v = linW[vv*100 + k-128];
      else if (k == 255) v = linb[vv];
    }
    storeHL(ws, O_BLIN, O_BLINL, e, v);
  }
}

// ============ fused main: BT=32 rows, 512 thr = 8 waves, 2 blocks/CU ============
__global__ __launch_bounds__(512, 4)
void seq2seq_main(const int* __restrict__ encX, const int* __restrict__ decX,
                  const ushort_t* __restrict__ ws, float* __restrict__ out) {
  const int tid  = threadIdx.x;
  const int lane = tid & 63;
  const int w    = __builtin_amdgcn_readfirstlane(tid >> 6);
  const int cl   = lane & 15, g4 = lane >> 4;
  const int c    = w;                      // col-tile (valid w<7)
  const int b0   = blockIdx.x * BT;

  __shared__ alignas(16) ushort_t Ash[BT * 256];   // 16,384 B swizzled
  __shared__ alignas(16) ushort_t Esh[kS * EPL];   // 65,280 B: [s][32][102]; cols 100-101 = score float

  const ushort_t* BER   = ws + O_BE_R;
  const ushort_t* BEZ   = ws + O_BE_Z;
  const ushort_t* BENH  = ws + O_BE_NH;
  const ushort_t* BENHL = ws + O_BE_NHL;
  const ushort_t* BENX  = ws + O_BE_NX;
  const ushort_t* BENXL = ws + O_BE_NXL;
  const ushort_t* BDR   = ws + O_BD_R;
  const ushort_t* BDZ   = ws + O_BD_Z;
  const ushort_t* BDNC  = ws + O_BD_NC;
  const ushort_t* BDNCL = ws + O_BD_NCL;
  const ushort_t* BDNH  = ws + O_BD_NH;
  const ushort_t* BDNHL = ws + O_BD_NHL;
  const ushort_t* WATT  = ws + O_WATT;
  const ushort_t* BLIN  = ws + O_BLIN;
  const ushort_t* BLINL = ws + O_BLINL;

  float hreg[2][4];   // wave's 16 dims x 32 rows (2 rt x 4 i per lane)
#pragma unroll
  for (int rt = 0; rt < 2; ++rt)
#pragma unroll
    for (int i = 0; i < 4; ++i) hreg[rt][i] = 0.f;

  // threads 0..127: (row, slot-group) = (tid&31, tid>>5)
  auto onehot = [&](const int* X, int tt, int baseByte) {
    if (tid < 128) {
      const int row = tid & 31, grp = tid >> 5;
      const int tok = X[(b0 + row) * kS + tt];
#pragma unroll
      for (int p = 0; p < 4; ++p) {
        const int j0 = grp * 8 + 2 * p;
        if (j0 <= 26) {
          const uint lo = (j0 == tok || j0 == 27) ? 0x3F80u : 0u;
          const uint hi = (j0 + 1 == tok || j0 + 1 == 27) ? 0x3F80u : 0u;
          stA32(Ash, row, baseByte + j0 * 2, lo | (hi << 16));
        }
      }
    }
  };

  for (int i = tid; i < BT * 256 / 2; i += 512) ((uint*)Ash)[i] = 0u;
  __syncthreads();
  onehot(encX, 0, 200);
  __syncthreads();

  // ================= encoder =================
  for (int t = 0; t < kS; ++t) {
    if (w < 7) {
      f32x4 R[2], Zx[2], NHa[2], NXa[2];
#pragma unroll
      for (int rt = 0; rt < 2; ++rt) {
        R[rt] = f32x4{0,0,0,0}; Zx[rt] = f32x4{0,0,0,0};
        NHa[rt] = f32x4{0,0,0,0}; NXa[rt] = f32x4{0,0,0,0};
      }
#pragma unroll
      for (int kf = 0; kf < 4; ++kf) {
        s16x8 a[2];
#pragma unroll
        for (int rt = 0; rt < 2; ++rt) a[rt] = ldA(Ash, rt, kf, cl, g4);
        s16x8 br  = ldBF(BER,   c * 4 + kf, lane);
        s16x8 bz  = ldBF(BEZ,   c * 4 + kf, lane);
        s16x8 bh  = ldBF(BENH,  c * 4 + kf, lane);
        s16x8 bhl = ldBF(BENHL, c * 4 + kf, lane);
#pragma unroll
        for (int rt = 0; rt < 2; ++rt) {
          R[rt]   = MF(a[rt], br, R[rt]);
          Zx[rt]  = MF(a[rt], bz, Zx[rt]);
          NHa[rt] = MF(a[rt], bh, NHa[rt]);
          NHa[rt] = MF(a[rt], bhl, NHa[rt]);
        }
        if (kf == 3) {
          s16x8 bx  = ldBF(BENX,  c, lane);
          s16x8 bxl = ldBF(BENXL, c, lane);
#pragma unroll
          for (int rt = 0; rt < 2; ++rt) {
            NXa[rt] = MF(a[rt], bx, NXa[rt]);
            NXa[rt] = MF(a[rt], bxl, NXa[rt]);
          }
        }
      }
#pragma unroll
      for (int rt = 0; rt < 2; ++rt)
#pragma unroll
        for (int i = 0; i < 4; ++i) {
          const float r = sigm(R[rt][i]);
          const float z = sigm(Zx[rt][i]);
          const float n = tanh_(NXa[rt][i] + r * NHa[rt][i]);
          hreg[rt][i] = (1.f - z) * n + z * hreg[rt][i];
        }
    }
    __syncthreads();
    if (w < 7) {
      const int d = 16 * c + cl;
      if (d < 100) {
#pragma unroll
        for (int rt = 0; rt < 2; ++rt)
#pragma unroll
          for (int i = 0; i < 4; ++i) {
            const int row = rt * 16 + g4 * 4 + i;
            const ushort_t us = f2b(hreg[rt][i]);
            Esh[t * EPL + row * ESTR + d] = us;
            stA16(Ash, row, (t < 9) ? d : 128 + d, us);
          }
      }
    }
    if (t < 9) onehot(encX, t + 1, 200);
    else       onehot(decX, 0, 456);
    __syncthreads();
  }

  // ================= decoder =================
  for (int t = 0; t < kS; ++t) {
    // ---- ph1: g = h @ attnW -> A cols 0..99 ----
    if (w < 7) {
      f32x4 G[2] = {f32x4{0,0,0,0}, f32x4{0,0,0,0}};
#pragma unroll
      for (int fi = 0; fi < 4; ++fi) {
        s16x8 bg = ldBF(WATT, c * 4 + fi, lane);
#pragma unroll
        for (int rt = 0; rt < 2; ++rt)
          G[rt] = MF(ldA(Ash, rt, 4 + fi, cl, g4), bg, G[rt]);
      }
      const int d = 16 * c + cl;
      if (d < 100) {
#pragma unroll
        for (int rt = 0; rt < 2; ++rt)
#pragma unroll
          for (int i = 0; i < 4; ++i)
            stA16(Ash, rt * 16 + g4 * 4 + i, d, f2b(G[rt][i]));
      }
    }
    __syncthreads();
    // ---- ph2: scores (wave w<5: planes 2w + lane>>5) -> Esh[.][r][100] ----
    if (w < 5) {
      const int s = 2 * w + (lane >> 5);
      const int r = lane & 31;
      const ushort_t* ep = Esh + s * EPL + r * ESTR;
      float acc = 0.f;
#pragma unroll
      for (int jj = 0; jj < 50; ++jj) {
        const uint gv = ldA32(Ash, r, jj * 4);
        const uint ev = *(const uint*)(ep + jj * 2);
        acc += lo16(gv) * lo16(ev) + hi16(gv) * hi16(ev);
      }
      *(float*)(ep + 100) = acc;
    }
    __syncthreads();
    // ---- ph3: softmax + ctx -> A cols 0..99 (16 workers/row) ----
    {
      const int r = lane & 31;
      const int W = w * 2 + (lane >> 5);   // 0..15
      float wat[10];
      {
        float sc[10];
#pragma unroll
        for (int s = 0; s < 10; ++s) sc[s] = *(const float*)(Esh + s * EPL + r * ESTR + 100);
        float m = sc[0];
#pragma unroll
        for (int s = 1; s < 10; ++s) m = fmaxf(m, sc[s]);
        float sum = 0.f;
#pragma unroll
        for (int s = 0; s < 10; ++s) { wat[s] = __expf(sc[s] - m); sum += wat[s]; }
        const float inv = 1.f / sum;
#pragma unroll
        for (int s = 0; s < 10; ++s) wat[s] *= inv;
      }
#pragma unroll
      for (int u = 0; u < 4; ++u) {
        const int j = W * 4 + u;          // uint index (pair of dims), 0..49 valid
        if (j < 50) {
          float v0 = 0.f, v1 = 0.f;
#pragma unroll
          for (int s = 0; s < 10; ++s) {
            const uint ev = *(const uint*)(Esh + s * EPL + r * ESTR + 2 * j);
            v0 += wat[s] * lo16(ev);
            v1 += wat[s] * hi16(ev);
          }
          stA32(Ash, r, 4 * j, (uint)f2b(v0) | ((uint)f2b(v1) << 16));
        }
      }
    }
    __syncthreads();
    // ---- ph4: GRU GEMMs + nonlin ----
    if (w < 7) {
      f32x4 R[2], Zx[2], NC[2], NHa[2];
#pragma unroll
      for (int rt = 0; rt < 2; ++rt) {
        R[rt] = f32x4{0,0,0,0}; Zx[rt] = f32x4{0,0,0,0};
        NC[rt] = f32x4{0,0,0,0}; NHa[rt] = f32x4{0,0,0,0};
      }
#pragma unroll
      for (int kf = 0; kf < 8; ++kf) {
        s16x8 a[2];
#pragma unroll
        for (int rt = 0; rt < 2; ++rt) a[rt] = ldA(Ash, rt, kf, cl, g4);
        s16x8 br = ldBF(BDR, c * 8 + kf, lane);
        s16x8 bz = ldBF(BDZ, c * 8 + kf, lane);
#pragma unroll
        for (int rt = 0; rt < 2; ++rt) {
          R[rt]  = MF(a[rt], br, R[rt]);
          Zx[rt] = MF(a[rt], bz, Zx[rt]);
        }
        if (kf < 4 || kf == 7) {
          const int fi = (kf < 4) ? kf : 4;
          s16x8 bnc  = ldBF(BDNC,  c * 5 + fi, lane);
          s16x8 bncl = ldBF(BDNCL, c * 5 + fi, lane);
#pragma unroll
          for (int rt = 0; rt < 2; ++rt) {
            NC[rt] = MF(a[rt], bnc, NC[rt]);
            NC[rt] = MF(a[rt], bncl, NC[rt]);
          }
        }
        if (kf >= 4) {
          const int fi = kf - 4;
          s16x8 bnh  = ldBF(BDNH,  c * 4 + fi, lane);
          s16x8 bnhl = ldBF(BDNHL, c * 4 + fi, lane);
#pragma unroll
          for (int rt = 0; rt < 2; ++rt) {
            NHa[rt] = MF(a[rt], bnh, NHa[rt]);
            NHa[rt] = MF(a[rt], bnhl, NHa[rt]);
          }
        }
      }
#pragma unroll
      for (int rt = 0; rt < 2; ++rt)
#pragma unroll
        for (int i = 0; i < 4; ++i) {
          const float r = sigm(R[rt][i]);
          const float z = sigm(Zx[rt][i]);
          const float n = tanh_(NC[rt][i] + r * NHa[rt][i]);
          hreg[rt][i] = (1.f - z) * n + z * hreg[rt][i];
        }
    }
    __syncthreads();
    // ---- ph5: h write (cols 128..227) + next onehot ----
    if (w < 7) {
      const int d = 16 * c + cl;
      if (d < 100) {
#pragma unroll
        for (int rt = 0; rt < 2; ++rt)
#pragma unroll
          for (int i = 0; i < 4; ++i)
            stA16(Ash, rt * 16 + g4 * 4 + i, 128 + d, f2b(hreg[rt][i]));
      }
    }
    if (t < 9) onehot(decX, t + 1, 456);
    __syncthreads();
    // ---- ph6: logits (4 wave-tasks), NT stores; disjoint vs next ph1 writes ----
    if (w < 4) {
      const int rtL = w >> 1, vt = w & 1;
      f32x4 aL = f32x4{0,0,0,0};
#pragma unroll
      for (int fi = 0; fi < 4; ++fi) {
        s16x8 a = ldA(Ash, rtL, 4 + fi, cl, g4);
        aL = MF(a, ldBF(BLIN,  vt * 4 + fi, lane), aL);
        aL = MF(a, ldBF(BLINL, vt * 4 + fi, lane), aL);
      }
      const int v = vt * 16 + cl;
      if (v < kV) {
#pragma unroll
        for (int i = 0; i < 4; ++i) {
          const int row = rtL * 16 + g4 * 4 + i;
          __builtin_nontemporal_store(aL[i], &out[((size_t)(b0 + row) * kS + t) * kV + v]);
        }
      }
    }
  }
}

extern "C" void kernel_launch(void* const* d_in, const int* in_sizes, int n_in,
                              void* d_out, int out_size, void* d_ws, size_t ws_size,
                              hipStream_t stream) {
  const int*   encX = (const int*)d_in[0];
  const int*   decX = (const int*)d_in[1];
  const float* emb  = (const float*)d_in[2];
  const float* eWih = (const float*)d_in[3];
  const float* eWhh = (const float*)d_in[4];
  const float* ebih = (const float*)d_in[5];
  const float* ebhh = (const float*)d_in[6];
  const float* dWih = (const float*)d_in[7];
  const float* dWhh = (const float*)d_in[8];
  const float* dbih = (const float*)d_in[9];
  const float* dbhh = (const float*)d_in[10];
  const float* attW = (const float*)d_in[11];
  const float* linW = (const float*)d_in[12];
  const float* linb = (const float*)d_in[13];
  ushort_t* ws = (ushort_t*)d_ws;
  float* o = (float*)d_out;

  seq2seq_setup<<<128, 256, 0, stream>>>(emb, eWih, eWhh, ebih, ebhh,
                                         dWih, dWhh, dbih, dbhh, attW, linW, linb, ws);
  seq2seq_main<<<NB, 512, 0, stream>>>(encX, decX, ws, o);
}

// Round 7
// 427.867 us; speedup vs baseline: 1.7201x; 1.7201x over previous
//
#include <hip/hip_runtime.h>
#include <hip/hip_bf16.h>

typedef short s16x8 __attribute__((ext_vector_type(8)));
typedef float f32x4 __attribute__((ext_vector_type(4)));
typedef unsigned short ushort_t;
typedef unsigned int uint;

#define DEV static __device__ __forceinline__

namespace {
constexpr int kV = 27, kS = 10, kB = 32768;
constexpr int BT = 32, NB = kB / BT;   // 1024 blocks, 2 blocks/CU (LDS+VGPR both allow exactly 2)

// fragment-ordered blob offsets (ushort units): [(tile*nF+fi)*512 + lane*8 + e]
constexpr size_t O_BE_R   = 0;
constexpr size_t O_BE_Z   = O_BE_R   + (size_t)7*4*512;
constexpr size_t O_BE_NH  = O_BE_Z   + (size_t)7*4*512;
constexpr size_t O_BE_NHL = O_BE_NH  + (size_t)7*4*512;
constexpr size_t O_BE_NX  = O_BE_NHL + (size_t)7*4*512;
constexpr size_t O_BE_NXL = O_BE_NX  + (size_t)7*1*512;
constexpr size_t O_BD_R   = O_BE_NXL + (size_t)7*1*512;
constexpr size_t O_BD_Z   = O_BD_R   + (size_t)7*8*512;
constexpr size_t O_BD_NC  = O_BD_Z   + (size_t)7*8*512;   // frags {0,1,2,3,7}
constexpr size_t O_BD_NCL = O_BD_NC  + (size_t)7*5*512;
constexpr size_t O_BD_NH  = O_BD_NCL + (size_t)7*5*512;   // frags {4,5,6,7}
constexpr size_t O_BD_NHL = O_BD_NH  + (size_t)7*4*512;
constexpr size_t O_WATT   = O_BD_NHL + (size_t)7*4*512;   // frags {4,5,6,7}
constexpr size_t O_BLIN   = O_WATT   + (size_t)7*4*512;   // frags {4,5,6,7}
constexpr size_t O_BLINL  = O_BLIN   + (size_t)2*4*512;

constexpr int ESTR = 102;              // Esh row stride (ushorts): 51 words, gcd(51,32)=1
constexpr int EPL  = BT * ESTR;        // per-s plane = 3264 ushorts
} // namespace

DEV float sigm(float x) { return 1.f / (1.f + __expf(-x)); }
DEV float tanh_(float x) {
  const float ax = fabsf(x), t = __expf(-2.f * ax);
  return copysignf((1.f - t) / (1.f + t), x);
}
DEV ushort_t f2b(float f) { return __builtin_bit_cast(ushort_t, __float2bfloat16(f)); }
DEV float b2f(ushort_t u) { return __builtin_bit_cast(float, (uint)u << 16); }
DEV float lo16(uint u) { return __builtin_bit_cast(float, u << 16); }
DEV float hi16(uint u) { return __builtin_bit_cast(float, u & 0xFFFF0000u); }
DEV f32x4 MF(s16x8 a, s16x8 b, f32x4 c) {
  return __builtin_amdgcn_mfma_f32_16x16x32_bf16(a, b, c, 0, 0, 0);
}
DEV float dot64(const float* __restrict__ a, const float* __restrict__ b) {
  float s = 0.f;
#pragma unroll 16
  for (int k = 0; k < 64; ++k) s += a[k] * b[k];
  return s;
}
DEV void storeHL(ushort_t* ws, size_t offH, size_t offL, int e, float v) {
  const ushort_t h = f2b(v);
  ws[offH + e] = h;
  ws[offL + e] = f2b(v - b2f(h));
}

// fragment-ordered B load: one coalesced 1KB block per (tile,frag)
DEV s16x8 ldBF(const ushort_t* p, int fragIdx, int lane) {
  return __builtin_bit_cast(s16x8, *(const uint4*)(p + ((size_t)fragIdx << 9) + (lane << 3)));
}
// swizzled A-tile (row stride 512B, XOR (row&7)<<4)
DEV uint swzb(int row, int byteoff) { return (uint)((row * 512 + byteoff) ^ ((row & 7) << 4)); }
DEV s16x8 ldA(const ushort_t* A, int rt, int kf, int cl, int g4) {
  const int row = rt * 16 + cl;
  return __builtin_bit_cast(s16x8, *(const uint4*)((const char*)A + swzb(row, kf * 64 + g4 * 16)));
}
DEV void stA16(ushort_t* A, int row, int col, ushort_t v) {
  *(ushort_t*)((char*)A + swzb(row, col * 2)) = v;
}
DEV void stA32(ushort_t* A, int row, int byteoff, uint v) {
  *(uint*)((char*)A + swzb(row, byteoff)) = v;
}
DEV uint ldA32(const ushort_t* A, int row, int byteoff) {
  return *(const uint*)((const char*)A + swzb(row, byteoff));
}

// ============ setup (unchanged) ============
// Encoder A (K=128): [h 0..99 | oh 100..126 | const1 @127]
// Decoder A (K=256): [ctx 0..99 | pad | h 128..227 | oh 228..254 | const1 @255]
__global__ void seq2seq_setup(const float* __restrict__ emb,
    const float* __restrict__ eWih, const float* __restrict__ eWhh,
    const float* __restrict__ ebih, const float* __restrict__ ebhh,
    const float* __restrict__ dWih, const float* __restrict__ dWhh,
    const float* __restrict__ dbih, const float* __restrict__ dbhh,
    const float* __restrict__ attnW, const float* __restrict__ linW,
    const float* __restrict__ linb, ushort_t* __restrict__ ws) {
  const int t0 = blockIdx.x * blockDim.x + threadIdx.x;
  const int stp = gridDim.x * blockDim.x;

  for (int e = t0; e < 7 * 4 * 512; e += stp) {
    int c = e >> 11, rem = e & 2047, fi = rem >> 9, l = (rem >> 3) & 63, i8 = rem & 7;
    int d = 16 * c + (l & 15);
    int k = fi * 32 + ((l >> 4) << 3) + i8;
    float vr = 0, vz = 0, vnh = 0;
    if (d < 100) {
      if (k < 100) { vr = eWhh[d*100+k]; vz = eWhh[(100+d)*100+k]; vnh = eWhh[(200+d)*100+k]; }
      else if (k < 127) {
        int tok = k - 100;
        vr = dot64(emb + tok*64, eWih + (size_t)d*64);
        vz = dot64(emb + tok*64, eWih + (size_t)(100+d)*64);
      } else {
        vr = ebih[d] + ebhh[d]; vz = ebih[100+d] + ebhh[100+d]; vnh = ebhh[200+d];
      }
    }
    ws[O_BE_R + e] = f2b(vr);
    ws[O_BE_Z + e] = f2b(vz);
    storeHL(ws, O_BE_NH, O_BE_NHL, e, vnh);
  }
  for (int e = t0; e < 7 * 512; e += stp) {
    int c = e >> 9, l = (e >> 3) & 63, i8 = e & 7;
    int d = 16 * c + (l & 15);
    int k = 96 + ((l >> 4) << 3) + i8;
    float v = 0;
    if (d < 100) {
      if (k >= 100 && k < 127) v = dot64(emb + (k-100)*64, eWih + (size_t)(200+d)*64);
      else if (k == 127) v = ebih[200+d];
    }
    storeHL(ws, O_BE_NX, O_BE_NXL, e, v);
  }
  for (int e = t0; e < 7 * 8 * 512; e += stp) {
    int c = e >> 12, rem = e & 4095, fi = rem >> 9, l = (rem >> 3) & 63, i8 = rem & 7;
    int d = 16 * c + (l & 15);
    int k = fi * 32 + ((l >> 4) << 3) + i8;
    float vr = 0, vz = 0;
    if (d < 100) {
      int wr = d, wz = 100 + d;
      if (k < 100)       { vr = dWih[(size_t)wr*164+64+k]; vz = dWih[(size_t)wz*164+64+k]; }
      else if (k < 128)  { }
      else if (k < 228)  { vr = dWhh[wr*100+k-128];        vz = dWhh[wz*100+k-128]; }
      else if (k < 255)  { vr = dot64(emb+(k-228)*64, dWih+(size_t)wr*164);
                           vz = dot64(emb+(k-228)*64, dWih+(size_t)wz*164); }
      else               { vr = dbih[wr]+dbhh[wr];         vz = dbih[wz]+dbhh[wz]; }
    }
    ws[O_BD_R + e] = f2b(vr);
    ws[O_BD_Z + e] = f2b(vz);
  }
  for (int e = t0; e < 7 * 5 * 512; e += stp) {
    int c = e / (5*512), rem = e - c*5*512, fi = rem >> 9, l = (rem >> 3) & 63, i8 = rem & 7;
    int fid = (fi < 4) ? fi : 7;
    int d = 16 * c + (l & 15);
    int k = fid * 32 + ((l >> 4) << 3) + i8;
    float v = 0;
    if (d < 100) {
      int wr = 200 + d;
      if (k < 100) v = dWih[(size_t)wr*164+64+k];
      else if (k >= 228 && k < 255) v = dot64(emb+(k-228)*64, dWih+(size_t)wr*164);
      else if (k == 255) v = dbih[wr];
    }
    storeHL(ws, O_BD_NC, O_BD_NCL, e, v);
  }
  for (int e = t0; e < 7 * 4 * 512; e += stp) {
    int c = e >> 11, rem = e & 2047, fi = rem >> 9, l = (rem >> 3) & 63, i8 = rem & 7;
    int d = 16 * c + (l & 15);
    int k = (4 + fi) * 32 + ((l >> 4) << 3) + i8;
    float v = 0;
    if (d < 100) {
      int wr = 200 + d;
      if (k >= 128 && k < 228) v = dWhh[wr*100+k-128];
      else if (k == 255) v = dbhh[wr];
    }
    storeHL(ws, O_BD_NH, O_BD_NHL, e, v);
  }
  for (int e = t0; e < 7 * 4 * 512; e += stp) {
    int c = e >> 11, rem = e & 2047, fi = rem >> 9, l = (rem >> 3) & 63, i8 = rem & 7;
    int d = 16 * c + (l & 15);
    int k = (4 + fi) * 32 + ((l >> 4) << 3) + i8;
    float v = 0;
    if (d < 100 && k >= 128 && k < 228) v = attnW[(k-128)*100 + d];
    ws[O_WATT + e] = f2b(v);
  }
  for (int e = t0; e < 2 * 4 * 512; e += stp) {
    int c = e >> 11, rem = e & 2047, fi = rem >> 9, l = (rem >> 3) & 63, i8 = rem & 7;
    int vv = 16 * c + (l & 15);
    int k = (4 + fi) * 32 + ((l >> 4) << 3) + i8;
    float v = 0;
    if (vv < kV) {
      if (k >= 128 && k < 228) v = linW[vv*100 + k-128];
      else if (k == 255) v = linb[vv];
    }
    storeHL(ws, O_BLIN, O_BLINL, e, v);
  }
}

// ============ fused main: BT=32 rows, 512 thr = 8 waves, 2 blocks/CU, VGPR<=256 (no spills) ============
__global__ __launch_bounds__(512, 2)
void seq2seq_main(const int* __restrict__ encX, const int* __restrict__ decX,
                  const ushort_t* __restrict__ ws, float* __restrict__ out) {
  const int tid  = threadIdx.x;
  const int lane = tid & 63;
  const int w    = __builtin_amdgcn_readfirstlane(tid >> 6);
  const int cl   = lane & 15, g4 = lane >> 4;
  const int c    = w;                      // col-tile (valid w<7)
  const int b0   = blockIdx.x * BT;

  __shared__ alignas(16) ushort_t Ash[BT * 256];   // 16,384 B swizzled
  __shared__ alignas(16) ushort_t Esh[kS * EPL];   // 65,280 B: [s][32][102]; cols 100-101 = score float

  const ushort_t* BER   = ws + O_BE_R;
  const ushort_t* BEZ   = ws + O_BE_Z;
  const ushort_t* BENH  = ws + O_BE_NH;
  const ushort_t* BENHL = ws + O_BE_NHL;
  const ushort_t* BENX  = ws + O_BE_NX;
  const ushort_t* BENXL = ws + O_BE_NXL;
  const ushort_t* BDR   = ws + O_BD_R;
  const ushort_t* BDZ   = ws + O_BD_Z;
  const ushort_t* BDNC  = ws + O_BD_NC;
  const ushort_t* BDNCL = ws + O_BD_NCL;
  const ushort_t* BDNH  = ws + O_BD_NH;
  const ushort_t* BDNHL = ws + O_BD_NHL;
  const ushort_t* WATT  = ws + O_WATT;
  const ushort_t* BLIN  = ws + O_BLIN;
  const ushort_t* BLINL = ws + O_BLINL;

  float hreg[2][4];   // wave's 16 dims x 32 rows (2 rt x 4 i per lane)
#pragma unroll
  for (int rt = 0; rt < 2; ++rt)
#pragma unroll
    for (int i = 0; i < 4; ++i) hreg[rt][i] = 0.f;

  // threads 0..127: (row, slot-group) = (tid&31, tid>>5)
  auto onehot = [&](const int* X, int tt, int baseByte) {
    if (tid < 128) {
      const int row = tid & 31, grp = tid >> 5;
      const int tok = X[(b0 + row) * kS + tt];
#pragma unroll
      for (int p = 0; p < 4; ++p) {
        const int j0 = grp * 8 + 2 * p;
        if (j0 <= 26) {
          const uint lo = (j0 == tok || j0 == 27) ? 0x3F80u : 0u;
          const uint hi = (j0 + 1 == tok || j0 + 1 == 27) ? 0x3F80u : 0u;
          stA32(Ash, row, baseByte + j0 * 2, lo | (hi << 16));
        }
      }
    }
  };

  for (int i = tid; i < BT * 256 / 2; i += 512) ((uint*)Ash)[i] = 0u;
  __syncthreads();
  onehot(encX, 0, 200);
  __syncthreads();

  // ================= encoder =================
  for (int t = 0; t < kS; ++t) {
    if (w < 7) {
      f32x4 R[2], Zx[2], NHa[2], NXa[2];
#pragma unroll
      for (int rt = 0; rt < 2; ++rt) {
        R[rt] = f32x4{0,0,0,0}; Zx[rt] = f32x4{0,0,0,0};
        NHa[rt] = f32x4{0,0,0,0}; NXa[rt] = f32x4{0,0,0,0};
      }
#pragma unroll
      for (int kf = 0; kf < 4; ++kf) {
        s16x8 a[2];
#pragma unroll
        for (int rt = 0; rt < 2; ++rt) a[rt] = ldA(Ash, rt, kf, cl, g4);
        s16x8 br  = ldBF(BER,   c * 4 + kf, lane);
        s16x8 bz  = ldBF(BEZ,   c * 4 + kf, lane);
        s16x8 bh  = ldBF(BENH,  c * 4 + kf, lane);
        s16x8 bhl = ldBF(BENHL, c * 4 + kf, lane);
#pragma unroll
        for (int rt = 0; rt < 2; ++rt) {
          R[rt]   = MF(a[rt], br, R[rt]);
          Zx[rt]  = MF(a[rt], bz, Zx[rt]);
          NHa[rt] = MF(a[rt], bh, NHa[rt]);
          NHa[rt] = MF(a[rt], bhl, NHa[rt]);
        }
        if (kf == 3) {
          s16x8 bx  = ldBF(BENX,  c, lane);
          s16x8 bxl = ldBF(BENXL, c, lane);
#pragma unroll
          for (int rt = 0; rt < 2; ++rt) {
            NXa[rt] = MF(a[rt], bx, NXa[rt]);
            NXa[rt] = MF(a[rt], bxl, NXa[rt]);
          }
        }
      }
#pragma unroll
      for (int rt = 0; rt < 2; ++rt)
#pragma unroll
        for (int i = 0; i < 4; ++i) {
          const float r = sigm(R[rt][i]);
          const float z = sigm(Zx[rt][i]);
          const float n = tanh_(NXa[rt][i] + r * NHa[rt][i]);
          hreg[rt][i] = (1.f - z) * n + z * hreg[rt][i];
        }
    }
    __syncthreads();
    if (w < 7) {
      const int d = 16 * c + cl;
      if (d < 100) {
#pragma unroll
        for (int rt = 0; rt < 2; ++rt)
#pragma unroll
          for (int i = 0; i < 4; ++i) {
            const int row = rt * 16 + g4 * 4 + i;
            const ushort_t us = f2b(hreg[rt][i]);
            Esh[t * EPL + row * ESTR + d] = us;
            stA16(Ash, row, (t < 9) ? d : 128 + d, us);
          }
      }
    }
    if (t < 9) onehot(encX, t + 1, 200);
    else       onehot(decX, 0, 456);
    __syncthreads();
  }

  // ================= decoder =================
  for (int t = 0; t < kS; ++t) {
    // ---- ph1: g = h @ attnW -> A cols 0..99 ----
    if (w < 7) {
      f32x4 G[2] = {f32x4{0,0,0,0}, f32x4{0,0,0,0}};
#pragma unroll
      for (int fi = 0; fi < 4; ++fi) {
        s16x8 bg = ldBF(WATT, c * 4 + fi, lane);
#pragma unroll
        for (int rt = 0; rt < 2; ++rt)
          G[rt] = MF(ldA(Ash, rt, 4 + fi, cl, g4), bg, G[rt]);
      }
      const int d = 16 * c + cl;
      if (d < 100) {
#pragma unroll
        for (int rt = 0; rt < 2; ++rt)
#pragma unroll
          for (int i = 0; i < 4; ++i)
            stA16(Ash, rt * 16 + g4 * 4 + i, d, f2b(G[rt][i]));
      }
    }
    __syncthreads();
    // ---- ph2: scores (wave w<5: planes 2w + lane>>5) -> Esh[.][r][100] ----
    if (w < 5) {
      const int s = 2 * w + (lane >> 5);
      const int r = lane & 31;
      const ushort_t* ep = Esh + s * EPL + r * ESTR;
      float acc = 0.f;
#pragma unroll
      for (int jj = 0; jj < 50; ++jj) {
        const uint gv = ldA32(Ash, r, jj * 4);
        const uint ev = *(const uint*)(ep + jj * 2);
        acc += lo16(gv) * lo16(ev) + hi16(gv) * hi16(ev);
      }
      *(float*)(ep + 100) = acc;
    }
    __syncthreads();
    // ---- ph3: softmax + ctx -> A cols 0..99 (16 workers/row) ----
    {
      const int r = lane & 31;
      const int W = w * 2 + (lane >> 5);   // 0..15
      float wat[10];
      {
        float sc[10];
#pragma unroll
        for (int s = 0; s < 10; ++s) sc[s] = *(const float*)(Esh + s * EPL + r * ESTR + 100);
        float m = sc[0];
#pragma unroll
        for (int s = 1; s < 10; ++s) m = fmaxf(m, sc[s]);
        float sum = 0.f;
#pragma unroll
        for (int s = 0; s < 10; ++s) { wat[s] = __expf(sc[s] - m); sum += wat[s]; }
        const float inv = 1.f / sum;
#pragma unroll
        for (int s = 0; s < 10; ++s) wat[s] *= inv;
      }
#pragma unroll
      for (int u = 0; u < 4; ++u) {
        const int j = W * 4 + u;          // uint index (pair of dims), 0..49 valid
        if (j < 50) {
          float v0 = 0.f, v1 = 0.f;
#pragma unroll
          for (int s = 0; s < 10; ++s) {
            const uint ev = *(const uint*)(Esh + s * EPL + r * ESTR + 2 * j);
            v0 += wat[s] * lo16(ev);
            v1 += wat[s] * hi16(ev);
          }
          stA32(Ash, r, 4 * j, (uint)f2b(v0) | ((uint)f2b(v1) << 16));
        }
      }
    }
    __syncthreads();
    // ---- ph4: GRU GEMMs + nonlin ----
    if (w < 7) {
      f32x4 R[2], Zx[2], NC[2], NHa[2];
#pragma unroll
      for (int rt = 0; rt < 2; ++rt) {
        R[rt] = f32x4{0,0,0,0}; Zx[rt] = f32x4{0,0,0,0};
        NC[rt] = f32x4{0,0,0,0}; NHa[rt] = f32x4{0,0,0,0};
      }
#pragma unroll
      for (int kf = 0; kf < 8; ++kf) {
        s16x8 a[2];
#pragma unroll
        for (int rt = 0; rt < 2; ++rt) a[rt] = ldA(Ash, rt, kf, cl, g4);
        s16x8 br = ldBF(BDR, c * 8 + kf, lane);
        s16x8 bz = ldBF(BDZ, c * 8 + kf, lane);
#pragma unroll
        for (int rt = 0; rt < 2; ++rt) {
          R[rt]  = MF(a[rt], br, R[rt]);
          Zx[rt] = MF(a[rt], bz, Zx[rt]);
        }
        if (kf < 4 || kf == 7) {
          const int fi = (kf < 4) ? kf : 4;
          s16x8 bnc  = ldBF(BDNC,  c * 5 + fi, lane);
          s16x8 bncl = ldBF(BDNCL, c * 5 + fi, lane);
#pragma unroll
          for (int rt = 0; rt < 2; ++rt) {
            NC[rt] = MF(a[rt], bnc, NC[rt]);
            NC[rt] = MF(a[rt], bncl, NC[rt]);
          }
        }
        if (kf >= 4) {
          const int fi = kf - 4;
          s16x8 bnh  = ldBF(BDNH,  c * 4 + fi, lane);
          s16x8 bnhl = ldBF(BDNHL, c * 4 + fi, lane);
#pragma unroll
          for (int rt = 0; rt < 2; ++rt) {
            NHa[rt] = MF(a[rt], bnh, NHa[rt]);
            NHa[rt] = MF(a[rt], bnhl, NHa[rt]);
          }
        }
      }
#pragma unroll
      for (int rt = 0; rt < 2; ++rt)
#pragma unroll
        for (int i = 0; i < 4; ++i) {
          const float r = sigm(R[rt][i]);
          const float z = sigm(Zx[rt][i]);
          const float n = tanh_(NC[rt][i] + r * NHa[rt][i]);
          hreg[rt][i] = (1.f - z) * n + z * hreg[rt][i];
        }
    }
    __syncthreads();
    // ---- ph5: h write (cols 128..227) + next onehot ----
    if (w < 7) {
      const int d = 16 * c + cl;
      if (d < 100) {
#pragma unroll
        for (int rt = 0; rt < 2; ++rt)
#pragma unroll
          for (int i = 0; i < 4; ++i)
            stA16(Ash, rt * 16 + g4 * 4 + i, 128 + d, f2b(hreg[rt][i]));
      }
    }
    if (t < 9) onehot(decX, t + 1, 456);
    __syncthreads();
    // ---- ph6: logits (4 wave-tasks), NT stores; disjoint vs next ph1 writes ----
    if (w < 4) {
      const int rtL = w >> 1, vt = w & 1;
      f32x4 aL = f32x4{0,0,0,0};
#pragma unroll
      for (int fi = 0; fi < 4; ++fi) {
        s16x8 a = ldA(Ash, rtL, 4 + fi, cl, g4);
        aL = MF(a, ldBF(BLIN,  vt * 4 + fi, lane), aL);
        aL = MF(a, ldBF(BLINL, vt * 4 + fi, lane), aL);
      }
      const int v = vt * 16 + cl;
      if (v < kV) {
#pragma unroll
        for (int i = 0; i < 4; ++i) {
          const int row = rtL * 16 + g4 * 4 + i;
          __builtin_nontemporal_store(aL[i], &out[((size_t)(b0 + row) * kS + t) * kV + v]);
        }
      }
    }
  }
}

extern "C" void kernel_launch(void* const* d_in, const int* in_sizes, int n_in,
                              void* d_out, int out_size, void* d_ws, size_t ws_size,
                              hipStream_t stream) {
  const int*   encX = (const int*)d_in[0];
  const int*   decX = (const int*)d_in[1];
  const float* emb  = (const float*)d_in[2];
  const float* eWih = (const float*)d_in[3];
  const float* eWhh = (const float*)d_in[4];
  const float* ebih = (const float*)d_in[5];
  const float* ebhh = (const float*)d_in[6];
  const float* dWih = (const float*)d_in[7];
  const float* dWhh = (const float*)d_in[8];
  const float* dbih = (const float*)d_in[9];
  const float* dbhh = (const float*)d_in[10];
  const float* attW = (const float*)d_in[11];
  const float* linW = (const float*)d_in[12];
  const float* linb = (const float*)d_in[13];
  ushort_t* ws = (ushort_t*)d_ws;
  float* o = (float*)d_out;

  seq2seq_setup<<<128, 256, 0, stream>>>(emb, eWih, eWhh, ebih, ebhh,
                                         dWih, dWhh, dbih, dbhh, attW, linW, linb, ws);
  seq2seq_main<<<NB, 512, 0, stream>>>(encX, decX, ws, o);
}